// Round 1
// baseline (3914.811 us; speedup 1.0000x reference)
//
#include <hip/hip_runtime.h>

typedef __bf16 bf16x8 __attribute__((ext_vector_type(8)));
typedef float f32x4 __attribute__((ext_vector_type(4)));

// ---------------- numerics helpers (bit-exact vs reference) ----------------

__device__ __forceinline__ unsigned short f32_to_bf16_bits(float v) {
  // values passed here are exactly representable in bf16 -> truncation is exact
  return (unsigned short)(__float_as_uint(v) >> 16);
}

__device__ __forceinline__ float round_e4m3_pos(float a) {
  // a >= 0. Matches _round_e4m3: e = clip(floor(log2(max(a,2^-9))), -6, 8)
  float am = fmaxf(a, 0x1p-9f);
  int e = (int)((__float_as_uint(am) >> 23) & 255) - 127;  // floor(log2), exact
  e = e < -6 ? -6 : (e > 8 ? 8 : e);
  float s = __int_as_float((e + 127) << 23);               // 2^e exact
  float q = rintf(a / s * 8.0f) * 0.125f * s;              // RNE like jnp.round
  return fminf(q, 448.0f);
}

__device__ __forceinline__ float round_e2m1(float x) {
  float a = fabsf(x);
  float am = fmaxf(a, 0x1p-3f);
  int e = (int)((__float_as_uint(am) >> 23) & 255) - 127;
  e = e < 0 ? 0 : (e > 2 ? 2 : e);
  float s = __int_as_float((e + 127) << 23);
  float q = rintf(a / s * 2.0f) * 0.5f * s;
  q = fminf(q, 6.0f);
  return x < 0.0f ? -q : q;
}

// async global->LDS, 16B per lane; LDS dest = wave-uniform base + lane*16
__device__ __forceinline__ void g2l16(const void* g, void* l) {
  __builtin_amdgcn_global_load_lds(
      (__attribute__((address_space(1))) void*)g,
      (__attribute__((address_space(3))) void*)l, 16, 0, 0);
}

// ---------------- prep kernels ----------------

__global__ void init_kernel(unsigned* p) {
  if (threadIdx.x < 2) p[threadIdx.x] = 0u;
}

__global__ __launch_bounds__(256) void amax_kernel(const float4* __restrict__ w,
                                                   unsigned* __restrict__ out, int n4) {
  float m = 0.0f;
  int stride = gridDim.x * 256;
  for (int i = blockIdx.x * 256 + threadIdx.x; i < n4; i += stride) {
    float4 v = w[i];
    m = fmaxf(m, fmaxf(fmaxf(fabsf(v.x), fabsf(v.y)), fmaxf(fabsf(v.z), fabsf(v.w))));
  }
#pragma unroll
  for (int o = 32; o > 0; o >>= 1) m = fmaxf(m, __shfl_xor(m, o, 64));
  if ((threadIdx.x & 63) == 0) atomicMax(out, __float_as_uint(m));
}

// one float4 per thread; 4 consecutive lanes own one 16-element block
__global__ __launch_bounds__(256) void quant_kernel(const float4* __restrict__ in,
                                                    ushort* __restrict__ outq,
                                                    const float* __restrict__ tsp,
                                                    const unsigned* __restrict__ amaxp,
                                                    int isw, int n4) {
  int i = blockIdx.x * 256 + threadIdx.x;
  if (i >= n4) return;
  float ts = isw ? (__uint_as_float(*amaxp) / 2688.0f) : *tsp;
  float4 v = in[i];
  float m = fmaxf(fmaxf(fabsf(v.x), fabsf(v.y)), fmaxf(fabsf(v.z), fabsf(v.w)));
  m = fmaxf(m, __shfl_xor(m, 1, 64));
  m = fmaxf(m, __shfl_xor(m, 2, 64));
  float bs = fmaxf(round_e4m3_pos(m / (6.0f * ts)), 0x1p-6f);
  float eff = bs * ts;
  float osc = isw ? bs : eff;  // weights: fold per-tensor ts out of the GEMM
  ushort4 o;
  o.x = f32_to_bf16_bits(round_e2m1(v.x / eff) * osc);
  o.y = f32_to_bf16_bits(round_e2m1(v.y / eff) * osc);
  o.z = f32_to_bf16_bits(round_e2m1(v.z / eff) * osc);
  o.w = f32_to_bf16_bits(round_e2m1(v.w / eff) * osc);
  *(ushort4*)(outq + (size_t)i * 4) = o;
}

// ---------------- GEMM (NT, both operands K-major), m97 structure ----------------
// EPI=0: out fp32 = acc * ts   EPI=1: out bf16 = nvfp4_fake_quant(gelu(acc*ts), tsh)

template <int EPI>
__global__ __launch_bounds__(256, 2) void gemm_nt(const ushort* __restrict__ A,
                                                  const ushort* __restrict__ B,
                                                  void* __restrict__ Out,
                                                  const unsigned* __restrict__ amaxp,
                                                  const float* __restrict__ tshp,
                                                  int N, int K) {
  __shared__ __align__(16) ushort ldsA[128 * 32];
  __shared__ __align__(16) ushort ldsB[128 * 32];
  const int tid = threadIdx.x;
  const int ntiles = N >> 7;
  const int bm = blockIdx.x / ntiles;
  const int bn = blockIdx.x - bm * ntiles;
  const size_t arow0 = (size_t)bm << 7;
  const size_t brow0 = (size_t)bn << 7;
  const int lane = tid & 63, wv = tid >> 6;
  const int wr = (wv >> 1) << 6, wc = (wv & 1) << 6;
  const int lr = lane & 15, lq = lane >> 4;

  f32x4 acc[4][4];
#pragma unroll
  for (int i = 0; i < 4; i++)
#pragma unroll
    for (int j = 0; j < 4; j++) {
      f32x4 z = {0.0f, 0.0f, 0.0f, 0.0f};
      acc[i][j] = z;
    }

  // staging chunk map: chunk c (16B) -> row c>>2, in-row 16B slot c&3
  const int c0 = tid, c1 = tid + 256;
  const ushort* gA0 = A + (arow0 + (size_t)(c0 >> 2)) * (size_t)K + (c0 & 3) * 8;
  const ushort* gA1 = A + (arow0 + (size_t)(c1 >> 2)) * (size_t)K + (c1 & 3) * 8;
  const ushort* gB0 = B + (brow0 + (size_t)(c0 >> 2)) * (size_t)K + (c0 & 3) * 8;
  const ushort* gB1 = B + (brow0 + (size_t)(c1 >> 2)) * (size_t)K + (c1 & 3) * 8;
  ushort* lA0 = &ldsA[c0 * 8];
  ushort* lA1 = &ldsA[c1 * 8];
  ushort* lB0 = &ldsB[c0 * 8];
  ushort* lB1 = &ldsB[c1 * 8];

  for (int k0 = 0; k0 < K; k0 += 32) {
    __syncthreads();
    g2l16(gA0 + k0, lA0);
    g2l16(gA1 + k0, lA1);
    g2l16(gB0 + k0, lB0);
    g2l16(gB1 + k0, lB1);
    __syncthreads();  // drains vmcnt -> LDS data visible
    bf16x8 af[4], bfr[4];
#pragma unroll
    for (int i = 0; i < 4; i++)
      af[i] = *(const bf16x8*)&ldsA[(wr + i * 16 + lr) * 32 + lq * 8];
#pragma unroll
    for (int j = 0; j < 4; j++)
      bfr[j] = *(const bf16x8*)&ldsB[(wc + j * 16 + lr) * 32 + lq * 8];
#pragma unroll
    for (int i = 0; i < 4; i++)
#pragma unroll
      for (int j = 0; j < 4; j++)
        acc[i][j] = __builtin_amdgcn_mfma_f32_16x16x32_bf16(af[i], bfr[j], acc[i][j], 0, 0, 0);
  }

  const float ts = __uint_as_float(*amaxp) / 2688.0f;
  if (EPI == 0) {
    float* o = (float*)Out;
#pragma unroll
    for (int i = 0; i < 4; i++)
#pragma unroll
      for (int j = 0; j < 4; j++) {
        size_t col = brow0 + wc + j * 16 + lr;
#pragma unroll
        for (int r = 0; r < 4; r++) {
          size_t row = arow0 + wr + i * 16 + lq * 4 + r;
          o[row * (size_t)N + col] = acc[i][j][r] * ts;
        }
      }
  } else {
    ushort* o = (ushort*)Out;
    const float tsh = *tshp;
#pragma unroll
    for (int i = 0; i < 4; i++)
#pragma unroll
      for (int j = 0; j < 4; j++) {
#pragma unroll
        for (int r = 0; r < 4; r++) {
          float h = acc[i][j][r] * ts;
          float g = 0.5f * h * (1.0f + erff(h * 0.707106781186547524f));
          // 16-col block amax: reduce over lanes sharing lq (bits 0..3)
          float m = fabsf(g);
          m = fmaxf(m, __shfl_xor(m, 1, 64));
          m = fmaxf(m, __shfl_xor(m, 2, 64));
          m = fmaxf(m, __shfl_xor(m, 4, 64));
          m = fmaxf(m, __shfl_xor(m, 8, 64));
          float bs = fmaxf(round_e4m3_pos(m / (6.0f * tsh)), 0x1p-6f);
          float eff = bs * tsh;
          float val = round_e2m1(g / eff) * eff;  // exact in bf16 (tsh = 96)
          size_t row = arow0 + wr + i * 16 + lq * 4 + r;
          size_t col = brow0 + wc + j * 16 + lr;
          o[row * (size_t)N + col] = f32_to_bf16_bits(val);
        }
      }
  }
}

// ---------------- launch ----------------

extern "C" void kernel_launch(void* const* d_in, const int* in_sizes, int n_in,
                              void* d_out, int out_size, void* d_ws, size_t ws_size,
                              hipStream_t stream) {
  const float* x = (const float*)d_in[0];
  const float* w1 = (const float*)d_in[1];
  const float* w2 = (const float*)d_in[2];
  const float* in_scale = (const float*)d_in[3];
  const float* hid_scale = (const float*)d_in[4];

  const int Bm = 8192, IN = 4096, HID = 16384, OUTN = 4096;

  unsigned* amax = (unsigned*)d_ws;
  ushort* xq = (ushort*)((char*)d_ws + 256);
  ushort* w1q = xq + (size_t)Bm * IN;
  ushort* w2q = w1q + (size_t)HID * IN;
  ushort* hq = w2q + (size_t)OUTN * HID;
  size_t need = 256 + 2 * ((size_t)Bm * IN + (size_t)HID * IN + (size_t)OUTN * HID +
                           (size_t)Bm * HID);
  if (ws_size < need) return;  // insufficient scratch; fail visibly

  init_kernel<<<1, 64, 0, stream>>>(amax);
  amax_kernel<<<2048, 256, 0, stream>>>((const float4*)w1, amax + 0, (HID * IN) / 4);
  amax_kernel<<<2048, 256, 0, stream>>>((const float4*)w2, amax + 1, (OUTN * HID) / 4);

  quant_kernel<<<(Bm * IN / 4) / 256, 256, 0, stream>>>((const float4*)x, xq, in_scale,
                                                        amax, 0, Bm * IN / 4);
  quant_kernel<<<(HID * IN / 4) / 256, 256, 0, stream>>>((const float4*)w1, w1q, in_scale,
                                                         amax + 0, 1, HID * IN / 4);
  quant_kernel<<<(OUTN * HID / 4) / 256, 256, 0, stream>>>((const float4*)w2, w2q, in_scale,
                                                           amax + 1, 1, OUTN * HID / 4);

  gemm_nt<1><<<(Bm / 128) * (HID / 128), 256, 0, stream>>>(xq, w1q, (void*)hq, amax + 0,
                                                           hid_scale, HID, IN);
  gemm_nt<0><<<(Bm / 128) * (OUTN / 128), 256, 0, stream>>>(hq, w2q, d_out, amax + 1,
                                                            hid_scale, OUTN, HID);
}